// Round 4
// baseline (152.477 us; speedup 1.0000x reference)
//
#include <hip/hip_runtime.h>

#define NROWS 8192
#define DIM   256

typedef __bf16 bf16x8 __attribute__((ext_vector_type(8)));
typedef __bf16 bf16x4 __attribute__((ext_vector_type(4)));
typedef float  f32x4  __attribute__((ext_vector_type(4)));

typedef __attribute__((address_space(3))) char lds_char;
typedef __attribute__((address_space(1))) const char glob_char;

#define LOG2E  1.4426950408889634f
#define NEG_HALF_LOG2E (-0.7213475204444817f)

#define BAR() asm volatile("s_barrier" ::: "memory")

// Cast x,y (f32) -> bf16; store pre-scaled norms px = -||x||^2 * log2e/2;
// zero the output scalar.
__global__ __launch_bounds__(256) void prep_kernel(
    const float* __restrict__ x, const float* __restrict__ y,
    __bf16* __restrict__ xb, __bf16* __restrict__ yb,
    float* __restrict__ px, float* __restrict__ py,
    float* __restrict__ out)
{
    int tid  = threadIdx.x;
    int lane = tid & 63;
    int w    = tid >> 6;
    int row  = blockIdx.x * 4 + w;          // 0 .. 16383
    bool isx = row < NROWS;
    int r    = isx ? row : row - NROWS;
    const float* src = (isx ? x : y) + (size_t)r * DIM;
    float4 v = reinterpret_cast<const float4*>(src)[lane];
    float sq = v.x*v.x + v.y*v.y + v.z*v.z + v.w*v.w;
    #pragma unroll
    for (int off = 32; off; off >>= 1) sq += __shfl_xor(sq, off);
    bf16x4 h;
    h[0] = (__bf16)v.x; h[1] = (__bf16)v.y; h[2] = (__bf16)v.z; h[3] = (__bf16)v.w;
    __bf16* dst = (isx ? xb : yb) + (size_t)r * DIM + lane * 4;
    *reinterpret_cast<bf16x4*>(dst) = h;
    if (lane == 0) (isx ? px : py)[r] = NEG_HALF_LOG2E * sq;
    if (blockIdx.x == 0 && tid == 0) out[0] = 0.0f;
}

// Persistent 4-tile blocks: grid = 256 (1/CU). Block (bm = blockIdx>>3,
// bng = blockIdx&7) computes output tiles (bm, bng*4 + t), t=0..3, as one
// 16-step K-stream (g = t*4+kt). 256x256 tile, BK=64, 8 waves (2x4),
// 4 phases/K-step, stage targets g+2 (16 loads in flight, vmcnt(8) —
// never drained until the end). Tile epilogues (exp2 sums) overlap the
// next tile's staging; px/py live in LDS so epilogue reads are lgkmcnt-
// domain and never force a vmcnt drain. Stage units are region-exact
// 16KB halves (A by m-range, B by n-range), each issued one barrier
// after its region's last ds_read (race-free; see R3 analysis).
__global__ __launch_bounds__(512, 1) void rbf_gemm_kernel(
    const __bf16* __restrict__ xb, const __bf16* __restrict__ yb,
    const float* __restrict__ px, const float* __restrict__ py,
    float* __restrict__ out)
{
    __shared__ __align__(16) char smem[136224];
    // [0,131072)       : 2 bufs x (A 32KB + B 32KB)
    // [131072,132096)  : px_lds, 256 f32 (this block's A-row norms)
    // [132096,136192)  : py_lds, 1024 f32 (norms for the 4 bn tiles)
    // [136192,136224)  : red[8]
    float* pxl = (float*)(smem + 131072);
    float* pyl = (float*)(smem + 132096);
    float* red = (float*)(smem + 136192);

    int tid  = threadIdx.x;
    int lane = tid & 63;
    int wv   = tid >> 6;            // 0..7
    int wm   = wv >> 2;             // 0..1 -> 128-row half
    int wn   = wv & 3;              // 0..3 -> 64-col quarter
    int bm   = blockIdx.x >> 3;     // 0..31
    int bng  = blockIdx.x & 7;      // bn group; == default XCD id -> B locality
    int h    = lane >> 4;
    int l15  = lane & 15;
    int arow = bm * 256;

    f32x4 acc[8][4];
    #pragma unroll
    for (int m = 0; m < 8; ++m)
        #pragma unroll
        for (int n = 0; n < 4; ++n)
            acc[m][n] = (f32x4){0.f, 0.f, 0.f, 0.f};

    // one stage unit = 16KB = 2 x global_load_lds(16B) per thread
    auto stage_unit = [&](int buf, int ktcol, int matrix, int unit, int baserow) {
        const __bf16* src = matrix ? yb : xb;
        #pragma unroll
        for (int j = 0; j < 2; ++j) {
            int lin = j * 8192 + tid * 16;
            int off;
            if (matrix == 0) off = unit * 8192 + lin + (lin >> 13) * 8192;
            else             off = unit * 4096 + lin + (lin >> 12) * 4096;
            int row = off >> 7;
            int kbs = (off & 127) ^ ((row & 7) << 4);
            size_t g = (size_t)(baserow + row) * 512 + (size_t)ktcol + kbs;
            __builtin_amdgcn_global_load_lds(
                (glob_char*)((const char*)src + g),
                (lds_char*)(smem + buf * 65536 + matrix * 32768 + off), 16, 0, 0);
        }
    };

    auto ldA = [&](int buf, int mbase, bf16x8* aF) {   // 8 ds_read_b128
        const char* Ab = smem + buf * 65536;
        #pragma unroll
        for (int m = 0; m < 4; ++m)
            #pragma unroll
            for (int kk = 0; kk < 2; ++kk) {
                int row = wm * 128 + (mbase + m) * 16 + l15;
                int kb  = (kk * 64 + h * 16) ^ ((row & 7) << 4);
                aF[m * 2 + kk] = *reinterpret_cast<const bf16x8*>(Ab + row * 128 + kb);
            }
    };
    auto ldB = [&](int buf, int nbase, bf16x8* bF) {   // 4 ds_read_b128
        const char* Bb = smem + buf * 65536 + 32768;
        #pragma unroll
        for (int n = 0; n < 2; ++n)
            #pragma unroll
            for (int kk = 0; kk < 2; ++kk) {
                int row = wn * 64 + (nbase + n) * 16 + l15;
                int kb  = (kk * 64 + h * 16) ^ ((row & 7) << 4);
                bF[n * 2 + kk] = *reinterpret_cast<const bf16x8*>(Bb + row * 128 + kb);
            }
    };
    auto mmaq = [&](int mbase, int nbase, bf16x8* aF, bf16x8* bF) {  // 16 MFMA
        __builtin_amdgcn_s_setprio(1);
        #pragma unroll
        for (int m = 0; m < 4; ++m)
            #pragma unroll
            for (int n = 0; n < 2; ++n)
                #pragma unroll
                for (int kk = 0; kk < 2; ++kk)
                    acc[mbase + m][nbase + n] = __builtin_amdgcn_mfma_f32_16x16x32_bf16(
                        aF[m * 2 + kk], bF[n * 2 + kk], acc[mbase + m][nbase + n], 0, 0, 0);
        __builtin_amdgcn_s_setprio(0);
    };

    // ---- prologue: px/py -> LDS (oldest in queue), then tiles g0,g1 ----
    if (tid < 256)
        __builtin_amdgcn_global_load_lds(
            (glob_char*)((const char*)(px + arow) + tid * 4),
            (lds_char*)((char*)pxl + tid * 4), 4, 0, 0);
    #pragma unroll
    for (int j = 0; j < 2; ++j)
        __builtin_amdgcn_global_load_lds(
            (glob_char*)((const char*)(py + bng * 1024) + j * 2048 + tid * 4),
            (lds_char*)((char*)pyl + j * 2048 + tid * 4), 4, 0, 0);
    int bn0row = bng * 4 * 256;
    stage_unit(0, 0,   0, 0, arow); stage_unit(0, 0,   1, 0, bn0row);
    stage_unit(0, 0,   1, 1, bn0row); stage_unit(0, 0,   0, 1, arow);
    stage_unit(1, 128, 0, 0, arow); stage_unit(1, 128, 1, 0, bn0row);
    stage_unit(1, 128, 1, 1, bn0row); stage_unit(1, 128, 0, 1, arow);
    asm volatile("s_waitcnt vmcnt(8)" ::: "memory");   // px/py + tile g0 landed
    BAR();

    // ---- main stream: 4 tiles x 4 K-steps x 4 phases ----
    float lsum = 0.f;
    for (int t = 0; t < 4; ++t) {
        #pragma unroll
        for (int kt = 0; kt < 4; ++kt) {
            int buf = kt & 1;                 // g = 4t+kt; g&1 == kt&1
            bool st = (t < 3) || (kt < 2);    // stage while g+2 <= 15
            int tgt_kt  = (kt + 2) & 3;
            int tgt_col = tgt_kt * 128;
            int tgt_bnrow = (bng * 4 + t + (kt >> 1)) * 256;
            bf16x8 aF[8], bF0[4], bF1[4];
            // q0: read A0+B0, MFMA m0-3 x n0-1
            ldA(buf, 0, aF);
            ldB(buf, 0, bF0);
            mmaq(0, 0, aF, bF0);
            BAR();
            // q1: read B1, stage A0+B0 of g+2, MFMA m0-3 x n2-3
            ldB(buf, 2, bF1);
            if (st) { stage_unit(buf, tgt_col, 0, 0, arow);
                      stage_unit(buf, tgt_col, 1, 0, tgt_bnrow); }
            mmaq(0, 2, aF, bF1);
            BAR();
            // q2: read A1, stage B1 of g+2, MFMA m4-7 x n2-3
            ldA(buf, 4, aF);
            if (st) stage_unit(buf, tgt_col, 1, 1, tgt_bnrow);
            mmaq(4, 2, aF, bF1);
            BAR();
            // q3: stage A1 of g+2, MFMA m4-7 x n0-1, counted vmcnt
            if (st) stage_unit(buf, tgt_col, 0, 1, arow);
            mmaq(4, 0, aF, bF0);
            if (st)            asm volatile("s_waitcnt vmcnt(8)" ::: "memory");
            else if (kt == 2)  asm volatile("s_waitcnt vmcnt(0)" ::: "memory");
            BAR();
        }
        // ---- tile epilogue (registers + LDS only; overlaps next staging) ----
        // C/D layout (verified): col = lane&15, row = (lane>>4)*4 + reg
        float py4[4];
        #pragma unroll
        for (int n = 0; n < 4; ++n)
            py4[n] = pyl[t * 256 + wn * 64 + n * 16 + l15];
        #pragma unroll
        for (int m = 0; m < 8; ++m) {
            f32x4 pxm = *reinterpret_cast<const f32x4*>(
                (const char*)pxl + (wm * 128 + m * 16 + h * 4) * 4);
            #pragma unroll
            for (int r = 0; r < 4; ++r) {
                float pv = pxm[r];
                #pragma unroll
                for (int n = 0; n < 4; ++n)
                    lsum += exp2f(fmaf(acc[m][n][r], LOG2E, pv + py4[n]));
            }
            #pragma unroll
            for (int n = 0; n < 4; ++n)
                acc[m][n] = (f32x4){0.f, 0.f, 0.f, 0.f};
        }
    }

    // ---- final reduction ----
    #pragma unroll
    for (int off = 32; off; off >>= 1) lsum += __shfl_xor(lsum, off);
    if (lane == 0) red[wv] = lsum;
    __syncthreads();
    if (tid == 0) {
        float s = (red[0] + red[1] + red[2] + red[3] +
                   red[4] + red[5] + red[6] + red[7]) * 1.4901161193847656e-08f;
        atomicAdd(out, s);
    }
}

extern "C" void kernel_launch(void* const* d_in, const int* in_sizes, int n_in,
                              void* d_out, int out_size, void* d_ws, size_t ws_size,
                              hipStream_t stream) {
    const float* x = (const float*)d_in[0];
    const float* y = (const float*)d_in[1];
    float* out = (float*)d_out;
    char* ws = (char*)d_ws;
    __bf16* xb = (__bf16*)ws;                                   // 4 MiB
    __bf16* yb = (__bf16*)(ws + (size_t)4 * 1024 * 1024);       // 4 MiB
    float*  px = (float*)(ws + (size_t)8 * 1024 * 1024);        // 32 KiB
    float*  py = (float*)(ws + (size_t)8 * 1024 * 1024 + 32 * 1024);

    hipLaunchKernelGGL(prep_kernel, dim3(4096), dim3(256), 0, stream,
                       x, y, xb, yb, px, py, out);
    hipLaunchKernelGGL(rbf_gemm_kernel, dim3(256), dim3(512), 0, stream,
                       xb, yb, px, py, out);
}

// Round 6
// 127.925 us; speedup vs baseline: 1.1919x; 1.1919x over previous
//
#include <hip/hip_runtime.h>

#define NROWS 8192
#define DIM   256

typedef __bf16 bf16x8 __attribute__((ext_vector_type(8)));
typedef __bf16 bf16x4 __attribute__((ext_vector_type(4)));
typedef float  f32x4  __attribute__((ext_vector_type(4)));

typedef __attribute__((address_space(3))) char lds_char;
typedef __attribute__((address_space(1))) const char glob_char;

#define LOG2E  1.4426950408889634f
#define NEG_HALF_LOG2E (-0.7213475204444817f)

#define BAR() asm volatile("s_barrier" ::: "memory")

// Cast x,y (f32) -> bf16; store pre-scaled norms px = -||x||^2 * log2e/2;
// zero the output scalar.
__global__ __launch_bounds__(256) void prep_kernel(
    const float* __restrict__ x, const float* __restrict__ y,
    __bf16* __restrict__ xb, __bf16* __restrict__ yb,
    float* __restrict__ px, float* __restrict__ py,
    float* __restrict__ out)
{
    int tid  = threadIdx.x;
    int lane = tid & 63;
    int w    = tid >> 6;
    int row  = blockIdx.x * 4 + w;          // 0 .. 16383
    bool isx = row < NROWS;
    int r    = isx ? row : row - NROWS;
    const float* src = (isx ? x : y) + (size_t)r * DIM;
    float4 v = reinterpret_cast<const float4*>(src)[lane];
    float sq = v.x*v.x + v.y*v.y + v.z*v.z + v.w*v.w;
    #pragma unroll
    for (int off = 32; off; off >>= 1) sq += __shfl_xor(sq, off);
    bf16x4 hh;
    hh[0] = (__bf16)v.x; hh[1] = (__bf16)v.y; hh[2] = (__bf16)v.z; hh[3] = (__bf16)v.w;
    __bf16* dst = (isx ? xb : yb) + (size_t)r * DIM + lane * 4;
    *reinterpret_cast<bf16x4*>(dst) = hh;
    if (lane == 0) (isx ? px : py)[r] = NEG_HALF_LOG2E * sq;
    if (blockIdx.x == 0 && tid == 0) out[0] = 0.0f;
}

// Persistent B-resident GEMM. Grid = 256 (1 block/CU).
//   c = blockIdx&7 (XCD), bmg = c>>1 (A row-group of 2048), bn = q*2+(c&1).
//   Per-XCD L2 working set: A panel 1 MB (shared by 32 blocks) + B 2 MB.
// Block: B panel (128 cols x K=256, 64 KB LDS, resident whole kernel);
// sweeps 8 M-tiles of 256 rows; A streams as 64 BK=32 slabs (16 KB) through
// a 5-slab ring, stage depth g+4, vmcnt(4) steady state (slab g+2 provably
// landed at each step's end; a stage always targets a slab whose reads
// completed before the previous barrier). h-major LDS layouts
// ([h][row][16B]) make A and B frag reads conflict-free with no swizzle.
// 8 waves as 4x2, wave-tile 64x64, 16 MFMA + 8 ds_read_b128 per step.
// px/py norms live in LDS (epilogue never touches the vmcnt domain).
__global__ __launch_bounds__(512, 1) void rbf_gemm_kernel(
    const __bf16* __restrict__ xb, const __bf16* __restrict__ yb,
    const float* __restrict__ px, const float* __restrict__ py,
    float* __restrict__ out)
{
    __shared__ __align__(16) char smem[156192];
    // [0,65536)        B: [kt:8][h:4][row:128][16B]
    // [65536,147456)   A ring: 5 slabs x 16 KB: [h:4][row:256][16B]
    // [147456,155648)  pxl: 2048 f32
    // [155648,156160)  pyl: 128 f32
    // [156160,156192)  red[8]
    float* pxl = (float*)(smem + 147456);
    float* pyl = (float*)(smem + 155648);
    float* red = (float*)(smem + 156160);

    int tid  = threadIdx.x;
    int lane = tid & 63;
    int wv   = tid >> 6;
    int wm   = wv >> 1;                 // 0..3: 64-row strip
    int wn   = wv & 1;                  // 0..1: 64-col strip
    int c    = blockIdx.x & 7;
    int bmg  = c >> 1;
    int bn   = (blockIdx.x >> 3) * 2 + (c & 1);
    int h    = lane >> 4;
    int l15  = lane & 15;
    int abase = bmg * 2048;
    int bbase = bn * 128;

    f32x4 acc[4][4];
    #pragma unroll
    for (int m = 0; m < 4; ++m)
        #pragma unroll
        for (int n = 0; n < 4; ++n)
            acc[m][n] = (f32x4){0.f, 0.f, 0.f, 0.f};

    auto stageA = [&](int s, int g) {               // 16 KB slab, 2 loads/thread
        int rowbase = abase + ((g >> 3) << 8);
        int ktcol   = (g & 7) << 6;
        char* dst0  = smem + 65536 + s * 16384;
        #pragma unroll
        for (int j = 0; j < 2; ++j) {
            int e  = j * 512 + tid;                 // elem16 in [0,1024)
            int hh = e >> 8, row = e & 255;
            __builtin_amdgcn_global_load_lds(
                (glob_char*)((const char*)xb + (size_t)(rowbase + row) * 512 + ktcol + hh * 16),
                (lds_char*)(dst0 + e * 16), 16, 0, 0);
        }
    };

    auto readA = [&](int s, bf16x8* a) {            // 4 ds_read_b128
        const char* base = smem + 65536 + s * 16384 + h * 4096 + (wm * 64 + l15) * 16;
        #pragma unroll
        for (int mf = 0; mf < 4; ++mf)
            a[mf] = *reinterpret_cast<const bf16x8*>(base + mf * 256);
    };
    auto readB = [&](int kt, bf16x8* b) {           // 4 ds_read_b128
        const char* base = smem + kt * 8192 + h * 2048 + (wn * 64 + l15) * 16;
        #pragma unroll
        for (int nf = 0; nf < 4; ++nf)
            b[nf] = *reinterpret_cast<const bf16x8*>(base + nf * 256);
    };
    auto mma = [&](bf16x8* a, bf16x8* b) {          // 16 MFMA
        __builtin_amdgcn_s_setprio(1);
        #pragma unroll
        for (int mf = 0; mf < 4; ++mf)
            #pragma unroll
            for (int nf = 0; nf < 4; ++nf)
                acc[mf][nf] = __builtin_amdgcn_mfma_f32_16x16x32_bf16(
                    a[mf], b[nf], acc[mf][nf], 0, 0, 0);
        __builtin_amdgcn_s_setprio(0);
    };

    float lsum = 0.f;
    float py4[4];

    auto epi = [&](int t) {
        const float* pxt = pxl + t * 256 + wm * 64;
        #pragma unroll
        for (int mf = 0; mf < 4; ++mf) {
            f32x4 pxv = *reinterpret_cast<const f32x4*>(pxt + mf * 16 + h * 4);
            #pragma unroll
            for (int r = 0; r < 4; ++r) {
                float pv = pxv[r];
                #pragma unroll
                for (int nf = 0; nf < 4; ++nf)
                    lsum += exp2f(fmaf(acc[mf][nf][r], LOG2E, pv + py4[nf]));
            }
            #pragma unroll
            for (int nf = 0; nf < 4; ++nf)
                acc[mf][nf] = (f32x4){0.f, 0.f, 0.f, 0.f};
        }
    };

    // ================= prologue =================
    if (wv == 0) {                                  // py: 128 f32, wave0 only
        #pragma unroll
        for (int j = 0; j < 2; ++j)
            __builtin_amdgcn_global_load_lds(
                (glob_char*)((const char*)(py + bbase + j * 64) + lane * 4),
                (lds_char*)((char*)pyl + j * 256 + lane * 4), 4, 0, 0);
    }
    #pragma unroll
    for (int j = 0; j < 8; ++j) {                   // B panel, 64 KB
        int e  = j * 512 + tid;                     // elem16 in [0,4096)
        int kt = e >> 9, hh = (e >> 7) & 3, row = e & 127;
        __builtin_amdgcn_global_load_lds(
            (glob_char*)((const char*)yb + (size_t)(bbase + row) * 512 + kt * 64 + hh * 16),
            (lds_char*)(smem + e * 16), 16, 0, 0);
    }
    __builtin_amdgcn_global_load_lds(               // px: 8 KB
        (glob_char*)((const char*)(px + abase) + tid * 16),
        (lds_char*)((char*)pxl + tid * 16), 16, 0, 0);
    stageA(0, 0); stageA(1, 1); stageA(2, 2); stageA(3, 3);
    asm volatile("s_waitcnt vmcnt(4)" ::: "memory"); // py,B,px,slab0,slab1 landed
    BAR();

    #pragma unroll
    for (int nf = 0; nf < 4; ++nf)
        py4[nf] = pyl[wn * 64 + nf * 16 + l15];

    bf16x8 aCur[4], bCur[4], aNxt[4], bNxt[4];
    readA(0, aCur); readB(0, bCur);

    // ================= main loop: g = 0..59 =================
    int s1 = 1, s4 = 4;                             // slab of g+1, slab of g+4
    int gg = 0;
    #pragma unroll 1
    for (int i = 0; i < 30; ++i) {
        stageA(s4, gg + 4);
        if (++s4 == 5) s4 = 0;
        readA(s1, aNxt); readB((gg + 1) & 7, bNxt);
        if (++s1 == 5) s1 = 0;
        mma(aCur, bCur);
        asm volatile("s_waitcnt vmcnt(4)" ::: "memory");
        BAR();
        ++gg;
        stageA(s4, gg + 4);
        if (++s4 == 5) s4 = 0;
        readA(s1, aCur); readB((gg + 1) & 7, bCur);
        if (++s1 == 5) s1 = 0;
        mma(aNxt, bNxt);
        if ((gg & 7) == 7) epi(gg >> 3);
        asm volatile("s_waitcnt vmcnt(4)" ::: "memory");
        BAR();
        ++gg;
    }

    // ================= tail: g = 60..63 (Cur = frags(60), s1 = 1) ========
    readA(s1, aNxt); readB(5, bNxt);                // frags(61)
    if (++s1 == 5) s1 = 0;
    mma(aCur, bCur);                                // g=60
    asm volatile("s_waitcnt vmcnt(2)" ::: "memory"); // slab 62 landed
    BAR();
    readA(s1, aCur); readB(6, bCur);                // frags(62)
    if (++s1 == 5) s1 = 0;
    mma(aNxt, bNxt);                                // g=61
    asm volatile("s_waitcnt vmcnt(0)" ::: "memory"); // slab 63 landed
    BAR();
    readA(s1, aNxt); readB(7, bNxt);                // frags(63)
    mma(aCur, bCur);                                // g=62
    BAR();
    mma(aNxt, bNxt);                                // g=63
    epi(7);

    // ================= reduction =================
    #pragma unroll
    for (int off = 32; off; off >>= 1) lsum += __shfl_xor(lsum, off);
    if (lane == 0) red[wv] = lsum;
    __syncthreads();
    if (tid == 0) {
        float s = (red[0] + red[1] + red[2] + red[3] +
                   red[4] + red[5] + red[6] + red[7]) * 1.4901161193847656e-08f;
        atomicAdd(out, s);
    }
}

extern "C" void kernel_launch(void* const* d_in, const int* in_sizes, int n_in,
                              void* d_out, int out_size, void* d_ws, size_t ws_size,
                              hipStream_t stream) {
    const float* x = (const float*)d_in[0];
    const float* y = (const float*)d_in[1];
    float* out = (float*)d_out;
    char* ws = (char*)d_ws;
    __bf16* xb = (__bf16*)ws;                                   // 4 MiB
    __bf16* yb = (__bf16*)(ws + (size_t)4 * 1024 * 1024);       // 4 MiB
    float*  px = (float*)(ws + (size_t)8 * 1024 * 1024);        // 32 KiB
    float*  py = (float*)(ws + (size_t)8 * 1024 * 1024 + 32 * 1024);

    hipLaunchKernelGGL(prep_kernel, dim3(4096), dim3(256), 0, stream,
                       x, y, xb, yb, px, py, out);
    hipLaunchKernelGGL(rbf_gemm_kernel, dim3(256), dim3(512), 0, stream,
                       xb, yb, px, py, out);
}

// Round 8
// 116.142 us; speedup vs baseline: 1.3128x; 1.1015x over previous
//
#include <hip/hip_runtime.h>
#include <hip/hip_fp8.h>

#define NROWS 8192
#define DIM   256

typedef float f32x4 __attribute__((ext_vector_type(4)));
typedef long  i64x2 __attribute__((ext_vector_type(2)));

typedef __attribute__((address_space(3))) char lds_char;
typedef __attribute__((address_space(1))) const char glob_char;

#define LOG2E  1.4426950408889634f
#define NEG_HALF_LOG2E (-0.7213475204444817f)

__device__ __forceinline__ int pack4_fp8(float a, float b, float c, float d) {
#if __has_builtin(__builtin_amdgcn_cvt_pk_fp8_f32)
    int pk = __builtin_amdgcn_cvt_pk_fp8_f32(a, b, 0, false);   // bytes 0,1
    pk     = __builtin_amdgcn_cvt_pk_fp8_f32(c, d, pk, true);   // bytes 2,3
    return pk;
#else
    union { unsigned char by[4]; int i; } u;
    u.by[0] = __hip_fp8_e4m3(a).__x;
    u.by[1] = __hip_fp8_e4m3(b).__x;
    u.by[2] = __hip_fp8_e4m3(c).__x;
    u.by[3] = __hip_fp8_e4m3(d).__x;
    return u.i;
#endif
}

// Cast x,y (f32) -> fp8 e4m3 in frag-ready permuted k-order; store pre-scaled
// norms px = -||x||^2*log2e/2 (f32, from unquantized values); zero the output.
// Permutation per 64-k tile: byte pos p = kt*64 + h*16 + s*8 + j holds
// original k = kt*64 + s*32 + h*8 + j. Applied identically to x and y, the
// dot product is unchanged, and a 16B LDS entry (h,row) = {kk0 frag, kk1 frag}
// for the 16x16x32 fp8 MFMA (per-lane 8 fp8 = i64), 16B-contiguous in global.
__global__ __launch_bounds__(256) void prep_kernel(
    const float* __restrict__ x, const float* __restrict__ y,
    unsigned char* __restrict__ xb, unsigned char* __restrict__ yb,
    float* __restrict__ px, float* __restrict__ py,
    float* __restrict__ out)
{
    int tid  = threadIdx.x;
    int lane = tid & 63;
    int w    = tid >> 6;
    int row  = blockIdx.x * 4 + w;          // 0 .. 16383
    bool isx = row < NROWS;
    int r    = isx ? row : row - NROWS;
    const float* src = (isx ? x : y) + (size_t)r * DIM;
    float4 v = reinterpret_cast<const float4*>(src)[lane];
    float sq = v.x*v.x + v.y*v.y + v.z*v.z + v.w*v.w;
    #pragma unroll
    for (int off = 32; off; off >>= 1) sq += __shfl_xor(sq, off);

    int pk = pack4_fp8(v.x, v.y, v.z, v.w);
    int k0 = lane * 4;
    int kt = k0 >> 6, q = k0 & 63;
    int s  = q >> 5, hh = (q >> 3) & 3, j0 = q & 7;                 // j0 in {0,4}
    int p0 = (kt << 6) + (hh << 4) + (s << 3) + j0;
    unsigned char* dst = (isx ? xb : yb) + (size_t)r * DIM + p0;
    *reinterpret_cast<int*>(dst) = pk;

    if (lane == 0) (isx ? px : py)[r] = NEG_HALF_LOG2E * sq;
    if (blockIdx.x == 0 && tid == 0) out[0] = 0.0f;
}

// fp8 GEMM, BM=256 x BN=128 tile, BK=64, double-buffered (48 KB LDS ->
// 2 blocks/CU, 16 waves/CU), simple 2-phase prefetch with __syncthreads
// (compiler-managed waits; sibling block hides drain stalls — m114 regime).
// 8 waves as 4x2, wave-tile 64x64, acc 4x4 (64 f32). LDS per buf:
//   A [h:4][row:256][16B] (16 KB), B [h:4][row:128][16B] (8 KB) — h-major
//   layout measured conflict-free in R6. One ds_read_b128 per frag pair:
//   v[0]=kk0 i64 frag, v[1]=kk1 (prep's permuted order).
// XCD map: bm = (b&7)*4 + (b>>9), bn = (b>>3)&63 — blocks on one XCD share
// 4 A-panels (256 KB); all fp8 data (4 MB) is L2-resident per XCD.
__global__ __launch_bounds__(512, 4) void rbf_gemm_kernel(
    const unsigned char* __restrict__ xb, const unsigned char* __restrict__ yb,
    const float* __restrict__ px, const float* __restrict__ py,
    float* __restrict__ out)
{
    __shared__ __align__(16) char smem[49152];   // 2 bufs x (A 16K + B 8K)
    __shared__ float red[8];

    int tid  = threadIdx.x;
    int lane = tid & 63;
    int wv   = tid >> 6;                // 0..7
    int wm   = wv >> 1;                 // 0..3: 64-row strip
    int wn   = wv & 1;                  // 0..1: 64-col strip
    int b    = blockIdx.x;
    int bm   = (b & 7) * 4 + (b >> 9);  // 0..31
    int bn   = (b >> 3) & 63;           // 0..63
    int h    = lane >> 4;
    int l15  = lane & 15;

    f32x4 acc[4][4];
    #pragma unroll
    for (int m = 0; m < 4; ++m)
        #pragma unroll
        for (int n = 0; n < 4; ++n)
            acc[m][n] = (f32x4){0.f, 0.f, 0.f, 0.f};

    auto stage = [&](int buf, int kt) {
        char* base = smem + buf * 24576;
        #pragma unroll
        for (int j = 0; j < 2; ++j) {                    // A: 1024 entries
            int e = j * 512 + tid;
            int hh = e >> 8, row = e & 255;
            __builtin_amdgcn_global_load_lds(
                (glob_char*)((const char*)xb + (size_t)(bm * 256 + row) * 256 + kt * 64 + hh * 16),
                (lds_char*)(base + e * 16), 16, 0, 0);
        }
        {                                                // B: 512 entries
            int e = tid;
            int hh = e >> 7, row = e & 127;
            __builtin_amdgcn_global_load_lds(
                (glob_char*)((const char*)yb + (size_t)(bn * 128 + row) * 256 + kt * 64 + hh * 16),
                (lds_char*)(base + 16384 + e * 16), 16, 0, 0);
        }
    };

    auto compute = [&](int buf) {
        const char* Ab = smem + buf * 24576;
        const char* Bb = Ab + 16384;
        i64x2 aF[4], bF[4];
        #pragma unroll
        for (int mf = 0; mf < 4; ++mf)
            aF[mf] = *reinterpret_cast<const i64x2*>(
                Ab + h * 4096 + (wm * 64 + mf * 16 + l15) * 16);
        #pragma unroll
        for (int nf = 0; nf < 4; ++nf)
            bF[nf] = *reinterpret_cast<const i64x2*>(
                Bb + h * 2048 + (wn * 64 + nf * 16 + l15) * 16);
        __builtin_amdgcn_s_setprio(1);
        #pragma unroll
        for (int mf = 0; mf < 4; ++mf)
            #pragma unroll
            for (int nf = 0; nf < 4; ++nf) {
                acc[mf][nf] = __builtin_amdgcn_mfma_f32_16x16x32_fp8_fp8(
                    aF[mf][0], bF[nf][0], acc[mf][nf], 0, 0, 0);
                acc[mf][nf] = __builtin_amdgcn_mfma_f32_16x16x32_fp8_fp8(
                    aF[mf][1], bF[nf][1], acc[mf][nf], 0, 0, 0);
            }
        __builtin_amdgcn_s_setprio(0);
    };

    stage(0, 0);
    __syncthreads();
    #pragma unroll
    for (int kt = 0; kt < 4; ++kt) {
        int buf = kt & 1;
        if (kt < 3) stage(buf ^ 1, kt + 1);
        compute(buf);
        __syncthreads();
    }

    // ---- epilogue: lsum += exp2(fma(dot, log2e, px+py)) ----
    // C/D layout (verified): col = lane&15, row = (lane>>4)*4 + reg
    float lsum = 0.f;
    int colbase = bn * 128 + wn * 64 + l15;
    int rowbase = bm * 256 + wm * 64 + h * 4;
    float py4[4];
    #pragma unroll
    for (int nf = 0; nf < 4; ++nf) py4[nf] = py[colbase + nf * 16];
    #pragma unroll
    for (int mf = 0; mf < 4; ++mf) {
        #pragma unroll
        for (int r = 0; r < 4; ++r) {
            float pv = px[rowbase + mf * 16 + r];
            #pragma unroll
            for (int nf = 0; nf < 4; ++nf)
                lsum += exp2f(fmaf(acc[mf][nf][r], LOG2E, pv + py4[nf]));
        }
    }
    #pragma unroll
    for (int off = 32; off; off >>= 1) lsum += __shfl_xor(lsum, off);
    if (lane == 0) red[wv] = lsum;
    __syncthreads();
    if (tid == 0) {
        float s = (red[0] + red[1] + red[2] + red[3] +
                   red[4] + red[5] + red[6] + red[7]) * 1.4901161193847656e-08f;
        atomicAdd(out, s);
    }
}

extern "C" void kernel_launch(void* const* d_in, const int* in_sizes, int n_in,
                              void* d_out, int out_size, void* d_ws, size_t ws_size,
                              hipStream_t stream) {
    const float* x = (const float*)d_in[0];
    const float* y = (const float*)d_in[1];
    float* out = (float*)d_out;
    char* ws = (char*)d_ws;
    unsigned char* xb = (unsigned char*)ws;                         // 2 MiB
    unsigned char* yb = (unsigned char*)(ws + (size_t)2 * 1024 * 1024);
    float* px = (float*)(ws + (size_t)4 * 1024 * 1024);             // 32 KiB
    float* py = (float*)(ws + (size_t)4 * 1024 * 1024 + 32 * 1024);

    hipLaunchKernelGGL(prep_kernel, dim3(4096), dim3(256), 0, stream,
                       x, y, xb, yb, px, py, out);
    hipLaunchKernelGGL(rbf_gemm_kernel, dim3(2048), dim3(512), 0, stream,
                       xb, yb, px, py, out);
}